// Round 7
// baseline (20601.315 us; speedup 1.0000x reference)
//
#include <hip/hip_runtime.h>
#include <cstdint>
#include <cstddef>

#define BATCH   8
#define NPTS    8192
#define NPOINT  2048
#define NSAMPLE 64
#define K0      67      // 3 + 64 input channels
#define C2      128

// Exact-order squared distance, matching XLA/numpy: ((dx*dx + dy*dy) + dz*dz),
// separate mul/add (no FMA contraction), round-to-nearest f32.
__device__ __forceinline__ float d2e(float ax, float ay, float az,
                                     float bx, float by, float bz) {
#pragma clang fp contract(off)
  float dx = ax - bx;
  float dy = ay - by;
  float dz = az - bz;
  float t0 = dx * dx;
  float t1 = dy * dy;
  float t2 = dz * dz;
  return (t0 + t1) + t2;
}

// ---- wave64 reductions via DPP; result broadcast via readlane (uniform).
__device__ __forceinline__ float dpp_max_f32(float x) {
  int v;
  v = __builtin_amdgcn_update_dpp(__float_as_int(x), __float_as_int(x), 0xB1, 0xF, 0xF, false);
  x = fmaxf(x, __int_as_float(v));
  v = __builtin_amdgcn_update_dpp(__float_as_int(x), __float_as_int(x), 0x4E, 0xF, 0xF, false);
  x = fmaxf(x, __int_as_float(v));
  v = __builtin_amdgcn_update_dpp(__float_as_int(x), __float_as_int(x), 0x141, 0xF, 0xF, false);
  x = fmaxf(x, __int_as_float(v));
  v = __builtin_amdgcn_update_dpp(__float_as_int(x), __float_as_int(x), 0x140, 0xF, 0xF, false);
  x = fmaxf(x, __int_as_float(v));
  v = __builtin_amdgcn_update_dpp(__float_as_int(x), __float_as_int(x), 0x142, 0xA, 0xF, false);
  x = fmaxf(x, __int_as_float(v));
  v = __builtin_amdgcn_update_dpp(__float_as_int(x), __float_as_int(x), 0x143, 0xC, 0xF, false);
  x = fmaxf(x, __int_as_float(v));
  return __int_as_float(__builtin_amdgcn_readlane(__float_as_int(x), 63));
}

__device__ __forceinline__ int dpp_min_i32(int x) {
  int v;
  v = __builtin_amdgcn_update_dpp(x, x, 0xB1, 0xF, 0xF, false); x = min(x, v);
  v = __builtin_amdgcn_update_dpp(x, x, 0x4E, 0xF, 0xF, false); x = min(x, v);
  v = __builtin_amdgcn_update_dpp(x, x, 0x141, 0xF, 0xF, false); x = min(x, v);
  v = __builtin_amdgcn_update_dpp(x, x, 0x140, 0xF, 0xF, false); x = min(x, v);
  v = __builtin_amdgcn_update_dpp(x, x, 0x142, 0xA, 0xF, false); x = min(x, v);
  v = __builtin_amdgcn_update_dpp(x, x, 0x143, 0xC, 0xF, false); x = min(x, v);
  return __builtin_amdgcn_readlane(x, 63);
}

// quartile of N(0,1)
__device__ __forceinline__ int quant4(float v) {
  return (v < -0.6745f) ? 0 : (v < 0.f) ? 1 : (v < 0.6745f) ? 2 : 3;
}

// pop next bucket id (0..127) from two 64-bit dirty masks; -1 if empty.
__device__ __forceinline__ int pop_bucket(unsigned long long& M0,
                                          unsigned long long& M1) {
  if (M0) { int b = (int)__builtin_ctzll(M0); M0 &= M0 - 1; return b; }
  if (M1) { int b = (int)__builtin_ctzll(M1); M1 &= M1 - 1; return 64 + b; }
  return -1;
}

// ---------------- FPS: single-wave serial loop, bucket-pruned ----------------
// Init (8 waves): counting-sort points into 128 buckets of 64 (serpentine
// 4x4x4 quartile cells), coords/dd/origidx stored SORTED in LDS, per-bucket
// bounding sphere + cmax. Loop (wave 0 only, NO barriers, NO global stores):
// rescan winner among buckets with cmax==gm (DPP min on orig idx = exact
// first-index tie-break), record slot in LDS, prune buckets vs
// dist(q,c_b) > r_b + sqrt(gm) (slack >> f32 rounding -> dd bit-exact),
// update dirty buckets (paired for latency overlap), refresh cmax registers.
// Final (8 waves): parallel writeback of inds + xyz from recorded slots.
__global__ __launch_bounds__(512) void fps_kernel(const float* __restrict__ xyz,
                                                  float* __restrict__ out_xyz,
                                                  float* __restrict__ out_inds) {
  const int b = blockIdx.x;
  const int tid = threadIdx.x;
  const int lane = tid & 63, w = tid >> 6;

  __shared__ float2 sxy[NPTS];                 // SORTED order
  __shared__ float  szl[NPTS];                 // SORTED
  __shared__ float  sdd[NPTS];                 // SORTED, current min-dist
  __shared__ unsigned short soi[NPTS];         // sorted slot -> orig idx
  __shared__ unsigned short sslot[NPOINT];     // winner slot per t
  __shared__ float4 bgeo[128];                 // cx,cy,cz,rb
  __shared__ float  bcm[128];                  // per-bucket max dd (init)
  __shared__ int hist[64], cbase[64], ccnt[64];
  __shared__ int slot0;

  const float* xb = xyz + (size_t)b * NPTS * 3;

  if (tid < 64) { hist[tid] = 0; ccnt[tid] = 0; }
  __syncthreads();

  // --- histogram of serpentine quartile cells
  float lx[16], ly[16], lz[16];
  int lc[16];
#pragma unroll
  for (int k = 0; k < 16; k++) {
    int i = tid + k * 512;
    float x = xb[i * 3 + 0], y = xb[i * 3 + 1], z = xb[i * 3 + 2];
    lx[k] = x; ly[k] = y; lz[k] = z;
    int qx_ = quant4(x), qy_ = quant4(y), qz_ = quant4(z);
    int yy = (qx_ & 1) ? 3 - qy_ : qy_;
    int zz = ((qx_ ^ yy) & 1) ? 3 - qz_ : qz_;
    int cell = qx_ * 16 + yy * 4 + zz;
    lc[k] = cell;
    atomicAdd(&hist[cell], 1);
  }
  __syncthreads();
  if (tid == 0) {
    int s = 0;
    for (int c = 0; c < 64; c++) { cbase[c] = s; s += hist[c]; }
  }
  __syncthreads();
  // --- scatter into sorted arrays
#pragma unroll
  for (int k = 0; k < 16; k++) {
    int i = tid + k * 512;
    int pos = cbase[lc[k]] + atomicAdd(&ccnt[lc[k]], 1);
    sxy[pos] = make_float2(lx[k], ly[k]);
    szl[pos] = lz[k];
    soi[pos] = (unsigned short)i;
    if (i == 0) slot0 = pos;
  }
  __syncthreads();

  const int s0 = slot0;
  const float2 q0xy = sxy[s0];
  const float q0x = q0xy.x, q0y = q0xy.y, q0z = szl[s0];

  // --- per-wave: init dd, bucket geometry + cmax for buckets w*16+j
#pragma unroll 1
  for (int j = 0; j < 16; j++) {
    int s = (w * 16 + j) * 64 + lane;
    float2 xy = sxy[s];
    float pxj = xy.x, pyj = xy.y, pzj = szl[s];
    float dd0 = d2e(pxj, pyj, pzj, q0x, q0y, q0z);
    sdd[s] = dd0;
    float xhi = dpp_max_f32(pxj), xlo = -dpp_max_f32(-pxj);
    float yhi = dpp_max_f32(pyj), ylo = -dpp_max_f32(-pyj);
    float zhi = dpp_max_f32(pzj), zlo = -dpp_max_f32(-pzj);
    float cx = 0.5f * (xlo + xhi), cy = 0.5f * (ylo + yhi), cz = 0.5f * (zlo + zhi);
    float r2 = dpp_max_f32(d2e(pxj, pyj, pzj, cx, cy, cz));
    float rb = sqrtf(r2) * 1.0002f + 1e-6f;    // certified over-estimate
    float cm = dpp_max_f32(dd0);
    if (lane == 0) {
      bgeo[w * 16 + j] = make_float4(cx, cy, cz, rb);
      bcm[w * 16 + j] = cm;
    }
  }
  __syncthreads();

  // ================= single-wave serial loop (no barriers) =================
  if (w == 0) {
    float4 bge0 = bgeo[lane], bge1 = bgeo[64 + lane];   // hoisted geometry
    float cml0 = bcm[lane],  cml1 = bcm[64 + lane];     // per-bucket cmax regs
    float gm = dpp_max_f32(fmaxf(cml0, cml1));
    if (lane == 0) sslot[0] = (unsigned short)s0;

    for (int t = 1; t < NPOINT; ++t) {
      // --- winner rescan among buckets with cmax == gm (usually one)
      unsigned long long bal0 = __ballot(cml0 == gm);
      unsigned long long bal1 = __ballot(cml1 == gm);
      int best_oi = 0x7FFFFFFF, best_slot = 0;
      for (;;) {
        int bkt = pop_bucket(bal0, bal1);
        if (bkt < 0) break;
        int base = bkt * 64 + lane;
        float dv = sdd[base];
        int ov = (int)soi[base];
        int cand = (dv == gm) ? ov : 0x7FFFFFFF;
        int mo = dpp_min_i32(cand);
        if (mo < best_oi) {
          best_oi = mo;
          unsigned long long wb = __ballot(cand == mo);
          best_slot = bkt * 64 + (int)(__ffsll(wb) - 1);
        }
      }
      if (lane == 0) sslot[t] = (unsigned short)best_slot;
      const float2 qxy = sxy[best_slot];
      const float qx = qxy.x, qy = qxy.y, qz = szl[best_slot];

      // --- prune: lane tests buckets {lane, 64+lane} (all in registers)
      const float sg = sqrtf(gm);
      float d2c0 = d2e(qx, qy, qz, bge0.x, bge0.y, bge0.z);
      float d2c1 = d2e(qx, qy, qz, bge1.x, bge1.y, bge1.z);
      float T0 = (bge0.w + sg) * 1.0005f + 1e-6f;
      float T1 = (bge1.w + sg) * 1.0005f + 1e-6f;
      unsigned long long m0 = __ballot(!(d2c0 > T0 * T0));
      unsigned long long m1 = __ballot(!(d2c1 > T1 * T1));

      // --- paired dirty-bucket update (overlap LDS latency)
      int ba = pop_bucket(m0, m1);
      while (ba >= 0) {
        int bb = pop_bucket(m0, m1);
        int sa = ba * 64 + lane;
        float2 xya = sxy[sa]; float za = szl[sa]; float da = sdd[sa];
        float2 xyb = make_float2(0.f, 0.f); float zb = 0.f, db = 0.f; int sb = 0;
        if (bb >= 0) { sb = bb * 64 + lane; xyb = sxy[sb]; zb = szl[sb]; db = sdd[sb]; }
        float nda = fminf(da, d2e(xya.x, xya.y, za, qx, qy, qz));
        sdd[sa] = nda;
        float vma = dpp_max_f32(nda);
        if (ba < 64) cml0 = (lane == ba) ? vma : cml0;
        else         cml1 = (lane == (ba - 64)) ? vma : cml1;
        if (bb >= 0) {
          float ndb = fminf(db, d2e(xyb.x, xyb.y, zb, qx, qy, qz));
          sdd[sb] = ndb;
          float vmb = dpp_max_f32(ndb);
          if (bb < 64) cml0 = (lane == bb) ? vmb : cml0;
          else         cml1 = (lane == (bb - 64)) ? vmb : cml1;
        }
        ba = pop_bucket(m0, m1);
      }
      gm = dpp_max_f32(fmaxf(cml0, cml1));
    }
  }
  __syncthreads();   // waves 1-7 wait here while wave 0 runs the loop

  // --- parallel writeback: inds + xyz from recorded slots
  for (int t = tid; t < NPOINT; t += 512) {
    int s = sslot[t];
    int o = (int)soi[s];
    float2 xy = sxy[s];
    out_inds[b * NPOINT + t] = (float)o;
    out_xyz[((size_t)b * NPOINT + t) * 3 + 0] = xy.x;
    out_xyz[((size_t)b * NPOINT + t) * 3 + 1] = xy.y;
    out_xyz[((size_t)b * NPOINT + t) * 3 + 2] = szl[s];
  }
}

// ---------------- prep: fold BN into per-channel consts ----------------------
// wsp floats: [0..255] A4[o]={sc0*W0x,sc0*W0y,sc0*W0z,sh0}; [256..319] sc1;
// [320..383] sh1; [384..511] sc2; [512..639] sh2; [640..703] sc0
__global__ __launch_bounds__(128) void prep_kernel(
    const float* __restrict__ W0, const float* __restrict__ g0,
    const float* __restrict__ b0, const float* __restrict__ m0,
    const float* __restrict__ v0, const float* __restrict__ g1,
    const float* __restrict__ b1, const float* __restrict__ m1,
    const float* __restrict__ v1, const float* __restrict__ g2,
    const float* __restrict__ b2, const float* __restrict__ m2,
    const float* __restrict__ v2, float* __restrict__ wsp) {
  const int tid = threadIdx.x;
  if (tid < 64) {
    float s0 = g0[tid] / sqrtf(v0[tid] + 1e-5f);
    wsp[4 * tid + 0] = s0 * W0[tid * K0 + 0];
    wsp[4 * tid + 1] = s0 * W0[tid * K0 + 1];
    wsp[4 * tid + 2] = s0 * W0[tid * K0 + 2];
    wsp[4 * tid + 3] = b0[tid] - m0[tid] * s0;
    wsp[640 + tid] = s0;
    float s1 = g1[tid] / sqrtf(v1[tid] + 1e-5f);
    wsp[256 + tid] = s1; wsp[320 + tid] = b1[tid] - m1[tid] * s1;
  }
  float s2 = g2[tid] / sqrtf(v2[tid] + 1e-5f);
  wsp[384 + tid] = s2; wsp[512 + tid] = b2[tid] - m2[tid] * s2;
}

// ---------------- zfeat: per-point L0 linear part ----------------------------
// szp[n][o] = sc0[o] * ( W0[o][0:3] . p_xyz + W0[o][3:67] . feat[:,n] )
__global__ __launch_bounds__(256) void zfeat_kernel(const float* __restrict__ xyz,
                                                    const float* __restrict__ feat,
                                                    const float* __restrict__ W0,
                                                    const float* __restrict__ wsp,
                                                    float* __restrict__ szp) {
  __shared__ float ftile[64][64];   // [c][u] - reads are wave-uniform
  __shared__ float sxyz[192];
  const int bt = blockIdx.x;        // b*128 + nt
  const int b = bt >> 7, nt = bt & 127;
  const int tid = threadIdx.x;
  const int lane = tid & 63, w = tid >> 6;

  const float* fb = feat + (size_t)b * 64 * NPTS + (size_t)nt * 64;
#pragma unroll
  for (int r = w; r < 64; r += 4)
    ftile[r][lane] = fb[(size_t)r * NPTS + lane];
  if (tid < 192)
    sxyz[tid] = xyz[((size_t)b * NPTS + (size_t)nt * 64) * 3 + tid];

  float w0x = W0[lane * K0 + 0], w0y = W0[lane * K0 + 1], w0z = W0[lane * K0 + 2];
  float wf[64];
#pragma unroll
  for (int i = 0; i < 64; i++) wf[i] = W0[lane * K0 + 3 + i];
  const float s0 = wsp[640 + lane];
  __syncthreads();

  float* ob = szp + ((size_t)b * NPTS + (size_t)nt * 64) * 64;
  for (int u = w; u < 64; u += 4) {
    float acc = w0x * sxyz[u * 3 + 0] + w0y * sxyz[u * 3 + 1] + w0z * sxyz[u * 3 + 2];
#pragma unroll
    for (int i = 0; i < 64; i++) acc = fmaf(wf[i], ftile[i][u], acc);
    ob[(size_t)u * 64 + lane] = acc * s0;
  }
}

// ---------------- ball query: one wave per query point -----------------------
__global__ __launch_bounds__(256) void ballq_kernel(const float* __restrict__ xyz,
                                                    const float* __restrict__ new_xyz,
                                                    int* __restrict__ ball) {
  const int lane = threadIdx.x & 63;
  const int q = blockIdx.x * 4 + (threadIdx.x >> 6);
  const int b = q >> 11;
  const float RR = (float)(0.4 * 0.4);
  const float cx = new_xyz[(size_t)q * 3 + 0];
  const float cy = new_xyz[(size_t)q * 3 + 1];
  const float cz = new_xyz[(size_t)q * 3 + 2];
  const float* xb = xyz + (size_t)b * NPTS * 3;
  int cnt = 0, firsti = -1;
  for (int base = 0; base < NPTS; base += 64) {
    int i = base + lane;
    float xx = xb[i * 3 + 0], yy = xb[i * 3 + 1], zz = xb[i * 3 + 2];
    float d2 = d2e(xx, yy, zz, cx, cy, cz);
    bool m = d2 < RR;
    unsigned long long mask = __ballot(m);
    if (mask) {
      if (firsti < 0) firsti = base + (__ffsll((unsigned long long)mask) - 1);
      int pos = cnt + (int)__popcll(mask & ((1ull << lane) - 1ull));
      if (m && pos < NSAMPLE) ball[(size_t)q * NSAMPLE + pos] = i;
      cnt += (int)__popcll(mask);
      if (cnt >= NSAMPLE) break;
    }
  }
  for (int s = cnt + lane; s < NSAMPLE; s += 64)
    ball[(size_t)q * NSAMPLE + s] = firsti;
}

// ---------------- MLP L1/L2 + max-pool: lane = channel, loop samples ---------
#define QPW 4
__global__ __launch_bounds__(256, 2) void mlp_kernel(
    const float* __restrict__ szp, const int* __restrict__ ball,
    const float* __restrict__ new_xyz, const float* __restrict__ W1,
    const float* __restrict__ W2, const float* __restrict__ wsp,
    float* __restrict__ out_feat) {
  __shared__ float ylds[4][64];
  __shared__ int   blds[4][64];
  const int tid = threadIdx.x;
  const int lane = tid & 63, wid = tid >> 6;

  float4 w1v[16], w2av[16], w2bv[16];
  const float4* W1r = (const float4*)(W1 + lane * 64);
  const float4* W2ar = (const float4*)(W2 + lane * 64);
  const float4* W2br = (const float4*)(W2 + (lane + 64) * 64);
#pragma unroll
  for (int i = 0; i < 16; i++) { w1v[i] = W1r[i]; w2av[i] = W2ar[i]; w2bv[i] = W2br[i]; }
  const float4 A = ((const float4*)wsp)[lane];
  const float sc1l = wsp[256 + lane], sh1l = wsp[320 + lane];
  const float sc2al = wsp[384 + lane], sh2al = wsp[512 + lane];
  const float sc2bl = wsp[448 + lane], sh2bl = wsp[576 + lane];

  for (int qi = 0; qi < QPW; qi++) {
    const int q = blockIdx.x * (4 * QPW) + qi * 4 + wid;
    const int b = q >> 11, p = q & 2047;

    const float cx = new_xyz[(size_t)q * 3 + 0];
    const float cy = new_xyz[(size_t)q * 3 + 1];
    const float cz = new_xyz[(size_t)q * 3 + 2];
    const float hc = A.w - (A.x * cx + A.y * cy + A.z * cz);

    blds[wid][lane] = ball[(size_t)q * NSAMPLE + lane];
    const float* szb = szp + (size_t)b * NPTS * 64;
    __builtin_amdgcn_s_waitcnt(0);   // vm+lgkm: blds visible to own wave

    float vA = 0.f, vB = 0.f;
    int idx0 = blds[wid][0];
    float fcur = szb[(size_t)idx0 * 64 + lane];
    const float4* yv = (const float4*)ylds[wid];

    for (int s = 0; s < NSAMPLE; s++) {
      int sn = (s < NSAMPLE - 1) ? s + 1 : s;
      int idxn = blds[wid][sn];
      float fnext = szb[(size_t)idxn * 64 + lane];

      float y0 = fmaxf(fcur + hc, 0.f);
      ylds[wid][lane] = y0;
      float a0 = 0.f, a1 = 0.f, a2 = 0.f, a3 = 0.f;
#pragma unroll
      for (int i = 0; i < 16; i++) {
        float4 y = yv[i];
        a0 = fmaf(w1v[i].x, y.x, a0);
        a1 = fmaf(w1v[i].y, y.y, a1);
        a2 = fmaf(w1v[i].z, y.z, a2);
        a3 = fmaf(w1v[i].w, y.w, a3);
      }
      float y1 = fmaxf(fmaf((a0 + a1) + (a2 + a3), sc1l, sh1l), 0.f);
      ylds[wid][lane] = y1;
      float c0 = 0.f, c1 = 0.f, c2 = 0.f, c3 = 0.f;
      float e0 = 0.f, e1 = 0.f, e2 = 0.f, e3 = 0.f;
#pragma unroll
      for (int i = 0; i < 16; i++) {
        float4 y = yv[i];
        c0 = fmaf(w2av[i].x, y.x, c0);
        c1 = fmaf(w2av[i].y, y.y, c1);
        c2 = fmaf(w2av[i].z, y.z, c2);
        c3 = fmaf(w2av[i].w, y.w, c3);
        e0 = fmaf(w2bv[i].x, y.x, e0);
        e1 = fmaf(w2bv[i].y, y.y, e1);
        e2 = fmaf(w2bv[i].z, y.z, e2);
        e3 = fmaf(w2bv[i].w, y.w, e3);
      }
      float y2a = fmaxf(fmaf((c0 + c1) + (c2 + c3), sc2al, sh2al), 0.f);
      float y2b = fmaxf(fmaf((e0 + e1) + (e2 + e3), sc2bl, sh2bl), 0.f);
      vA = fmaxf(vA, y2a);
      vB = fmaxf(vB, y2b);
      fcur = fnext;
    }
    out_feat[((size_t)b * C2 + lane) * NPOINT + p] = vA;
    out_feat[((size_t)b * C2 + lane + 64) * NPOINT + p] = vB;
  }
}

extern "C" void kernel_launch(void* const* d_in, const int* in_sizes, int n_in,
                              void* d_out, int out_size, void* d_ws, size_t ws_size,
                              hipStream_t stream) {
  const float* xyz  = (const float*)d_in[0];
  const float* feat = (const float*)d_in[1];
  const float* W0 = (const float*)d_in[2];
  const float* g0 = (const float*)d_in[3];
  const float* b0 = (const float*)d_in[4];
  const float* m0 = (const float*)d_in[5];
  const float* v0 = (const float*)d_in[6];
  const float* W1 = (const float*)d_in[7];
  const float* g1 = (const float*)d_in[8];
  const float* b1 = (const float*)d_in[9];
  const float* m1 = (const float*)d_in[10];
  const float* v1 = (const float*)d_in[11];
  const float* W2 = (const float*)d_in[12];
  const float* g2 = (const float*)d_in[13];
  const float* b2 = (const float*)d_in[14];
  const float* m2 = (const float*)d_in[15];
  const float* v2 = (const float*)d_in[16];

  float* out = (float*)d_out;
  float* out_xyz  = out;                         // (8,2048,3)   = 49152
  float* out_feat = out + 49152;                 // (8,128,2048) = 2097152
  float* out_inds = out + 49152 + 2097152;       // (8,2048)     = 16384

  int*   ball = (int*)d_ws;                                      // 4 MiB
  float* szp  = (float*)((char*)d_ws + 4194304);                 // 16.8 MiB
  float* wsp  = (float*)((char*)d_ws + 20971520);                // ~3 KiB

  hipLaunchKernelGGL(prep_kernel, dim3(1), dim3(128), 0, stream,
                     W0, g0, b0, m0, v0, g1, b1, m1, v1, g2, b2, m2, v2, wsp);
  hipLaunchKernelGGL(zfeat_kernel, dim3(BATCH * (NPTS / 64)), dim3(256), 0, stream,
                     xyz, feat, W0, wsp, szp);
  hipLaunchKernelGGL(fps_kernel, dim3(BATCH), dim3(512), 0, stream,
                     xyz, out_xyz, out_inds);
  hipLaunchKernelGGL(ballq_kernel, dim3((BATCH * NPOINT) / 4), dim3(256), 0, stream,
                     xyz, out_xyz, ball);
  hipLaunchKernelGGL(mlp_kernel, dim3((BATCH * NPOINT) / (4 * QPW)), dim3(256), 0, stream,
                     szp, ball, out_xyz, W1, W2, wsp, out_feat);
}

// Round 8
// 3949.500 us; speedup vs baseline: 5.2162x; 5.2162x over previous
//
#include <hip/hip_runtime.h>
#include <cstdint>
#include <cstddef>

#define BATCH   8
#define NPTS    8192
#define NPOINT  2048
#define NSAMPLE 64
#define K0      67      // 3 + 64 input channels
#define C2      128

// Exact-order squared distance, matching XLA/numpy: ((dx*dx + dy*dy) + dz*dz),
// separate mul/add (no FMA contraction), round-to-nearest f32.
__device__ __forceinline__ float d2e(float ax, float ay, float az,
                                     float bx, float by, float bz) {
#pragma clang fp contract(off)
  float dx = ax - bx;
  float dy = ay - by;
  float dz = az - bz;
  float t0 = dx * dx;
  float t1 = dy * dy;
  float t2 = dz * dz;
  return (t0 + t1) + t2;
}

// ---- wave64 reductions via DPP; result broadcast via readlane (uniform).
__device__ __forceinline__ float dpp_max_f32(float x) {
  int v;
  v = __builtin_amdgcn_update_dpp(__float_as_int(x), __float_as_int(x), 0xB1, 0xF, 0xF, false);
  x = fmaxf(x, __int_as_float(v));
  v = __builtin_amdgcn_update_dpp(__float_as_int(x), __float_as_int(x), 0x4E, 0xF, 0xF, false);
  x = fmaxf(x, __int_as_float(v));
  v = __builtin_amdgcn_update_dpp(__float_as_int(x), __float_as_int(x), 0x141, 0xF, 0xF, false);
  x = fmaxf(x, __int_as_float(v));
  v = __builtin_amdgcn_update_dpp(__float_as_int(x), __float_as_int(x), 0x140, 0xF, 0xF, false);
  x = fmaxf(x, __int_as_float(v));
  v = __builtin_amdgcn_update_dpp(__float_as_int(x), __float_as_int(x), 0x142, 0xA, 0xF, false);
  x = fmaxf(x, __int_as_float(v));
  v = __builtin_amdgcn_update_dpp(__float_as_int(x), __float_as_int(x), 0x143, 0xC, 0xF, false);
  x = fmaxf(x, __int_as_float(v));
  return __int_as_float(__builtin_amdgcn_readlane(__float_as_int(x), 63));
}

__device__ __forceinline__ int dpp_min_i32(int x) {
  int v;
  v = __builtin_amdgcn_update_dpp(x, x, 0xB1, 0xF, 0xF, false); x = min(x, v);
  v = __builtin_amdgcn_update_dpp(x, x, 0x4E, 0xF, 0xF, false); x = min(x, v);
  v = __builtin_amdgcn_update_dpp(x, x, 0x141, 0xF, 0xF, false); x = min(x, v);
  v = __builtin_amdgcn_update_dpp(x, x, 0x140, 0xF, 0xF, false); x = min(x, v);
  v = __builtin_amdgcn_update_dpp(x, x, 0x142, 0xA, 0xF, false); x = min(x, v);
  v = __builtin_amdgcn_update_dpp(x, x, 0x143, 0xC, 0xF, false); x = min(x, v);
  return __builtin_amdgcn_readlane(x, 63);
}

// quartile of N(0,1)
__device__ __forceinline__ int quant4(float v) {
  return (v < -0.6745f) ? 0 : (v < 0.f) ? 1 : (v < 0.6745f) ? 2 : 3;
}

// ---------------- FPS: bucket-pruned serial argmax, NO in-loop global stores -
// One block/batch, 8 waves. Points counting-sorted into 128 chunks of 64
// ("buckets") by serpentine 4x4x4 quartile cells. Wave w owns buckets w*16+j,
// lane l owns sorted slot bucket*64+l; dd lives in registers. Per iteration:
// all waves redundantly min-reduce the 8 wave keys -> winner (idx,gmax);
// winner INDEX is recorded in LDS (u16) -- the global writeback happens once,
// in parallel, after the loop, so no s_waitcnt vmcnt(0) store-drain sits in
// front of the per-iteration barrier. Prune: bucket skippable iff
// dist(q,c_b) > r_b + sqrt(gmax) (slack >> f32 rounding) -> dd bit-exact.
__global__ __launch_bounds__(512) void fps_kernel(const float* __restrict__ xyz,
                                                  float* __restrict__ out_xyz,
                                                  float* __restrict__ out_inds) {
  const int b = blockIdx.x;
  const int tid = threadIdx.x;
  const int lane = tid & 63, w = tid >> 6;

  __shared__ float2 sxy[NPTS];                  // ORIGINAL order (q lookup)
  __shared__ float  szl[NPTS];
  __shared__ int    soi[NPTS];                  // sorted slot -> orig idx
  __shared__ unsigned short sslot[NPOINT];      // winner orig idx per t
  __shared__ float4 bgeo[128];                  // cx,cy,cz,rb  [w*16+j]
  __shared__ unsigned long long wred[2][8] __attribute__((aligned(16)));
  __shared__ int hist[64], cbase[64], ccnt[64];

  const float* xb = xyz + (size_t)b * NPTS * 3;

  if (tid < 64) { hist[tid] = 0; ccnt[tid] = 0; }
  __syncthreads();

  // --- stage coords (original order) + histogram of serpentine quartile cells
  int lc[16];
#pragma unroll
  for (int k = 0; k < 16; k++) {
    int i = tid + k * 512;
    float x = xb[i * 3 + 0], y = xb[i * 3 + 1], z = xb[i * 3 + 2];
    sxy[i] = make_float2(x, y); szl[i] = z;
    int qx_ = quant4(x), qy_ = quant4(y), qz_ = quant4(z);
    int yy = (qx_ & 1) ? 3 - qy_ : qy_;
    int zz = ((qx_ ^ yy) & 1) ? 3 - qz_ : qz_;
    int cell = qx_ * 16 + yy * 4 + zz;
    lc[k] = cell;
    atomicAdd(&hist[cell], 1);
  }
  __syncthreads();
  if (tid == 0) {
    int s = 0;
    for (int c = 0; c < 64; c++) { cbase[c] = s; s += hist[c]; }
  }
  __syncthreads();
#pragma unroll
  for (int k = 0; k < 16; k++) {
    int pos = cbase[lc[k]] + atomicAdd(&ccnt[lc[k]], 1);
    soi[pos] = tid + k * 512;
  }
  __syncthreads();

  const float2 q0xy = sxy[0];
  const float q0x = q0xy.x, q0y = q0xy.y, q0z = szl[0];

  // --- gather owned points to regs, init dd, bucket geometry
  float px[16], py[16], pz[16], dd[16];
  int oi[16];
#pragma unroll
  for (int j = 0; j < 16; j++) {
    int s = (w * 16 + j) * 64 + lane;
    int o = soi[s];
    oi[j] = o;
    float2 pxy = sxy[o];
    px[j] = pxy.x; py[j] = pxy.y; pz[j] = szl[o];
    dd[j] = d2e(px[j], py[j], pz[j], q0x, q0y, q0z);
    float xhi = dpp_max_f32(px[j]), xlo = -dpp_max_f32(-px[j]);
    float yhi = dpp_max_f32(py[j]), ylo = -dpp_max_f32(-py[j]);
    float zhi = dpp_max_f32(pz[j]), zlo = -dpp_max_f32(-pz[j]);
    float cx = 0.5f * (xlo + xhi), cy = 0.5f * (ylo + yhi), cz = 0.5f * (zlo + zhi);
    float r2 = dpp_max_f32(d2e(px[j], py[j], pz[j], cx, cy, cz));
    float rb = sqrtf(r2) * 1.0002f + 1e-6f;      // certified over-estimate
    if (lane == 0) bgeo[w * 16 + j] = make_float4(cx, cy, cz, rb);
  }
  if (tid == 0) sslot[0] = 0;

  // --- initial wave key: per-thread tie-aware scan + DPP reduces
  unsigned long long wkey;
  {
    float bv = dd[0]; int boi = oi[0];
#pragma unroll
    for (int j = 1; j < 16; j++) {
      bool better = (dd[j] > bv) || (dd[j] == bv && oi[j] < boi);
      bv = better ? dd[j] : bv; boi = better ? oi[j] : boi;
    }
    float vm = dpp_max_f32(bv);
    int ci = (bv == vm) ? boi : 0x7FFFFFFF;
    int widx = dpp_min_i32(ci);
    wkey = ((unsigned long long)(~__float_as_uint(vm)) << 32) | (unsigned)widx;
  }
  if (lane == 0) wred[0][w] = wkey;
  __syncthreads();

  for (int t = 1; t < NPOINT; ++t) {
    // --- global winner = min of 8 wave keys (vectorized broadcast reads)
    const ulonglong2* wv = (const ulonglong2*)wred[(t - 1) & 1];
    ulonglong2 p0 = wv[0], p1 = wv[1], p2 = wv[2], p3 = wv[3];
    unsigned long long g0 = (p0.y < p0.x) ? p0.y : p0.x;
    unsigned long long g1 = (p1.y < p1.x) ? p1.y : p1.x;
    unsigned long long g2 = (p2.y < p2.x) ? p2.y : p2.x;
    unsigned long long g3 = (p3.y < p3.x) ? p3.y : p3.x;
    g0 = (g1 < g0) ? g1 : g0; g2 = (g3 < g2) ? g3 : g2;
    g0 = (g2 < g0) ? g2 : g0;
    const int nxt = (int)(g0 & 0xFFFFFFFFu);
    const float gmax = __uint_as_float(~(unsigned)(g0 >> 32));
    const float2 qxy = sxy[nxt];
    const float qx = qxy.x, qy = qxy.y, qz = szl[nxt];
    if (tid == 0) sslot[t] = (unsigned short)nxt;   // LDS only; no global store

    // --- prune check: lane jj tests bucket w*16+jj against uniform bound
    const float sg = sqrtf(gmax);
    const int jj = lane & 15;
    float4 g = bgeo[w * 16 + jj];
    float d2c = d2e(qx, qy, qz, g.x, g.y, g.z);
    float T = (g.w + sg) * 1.0005f + 1e-6f;
    bool dirty = !(d2c > T * T);
    unsigned dmask = (unsigned)__ballot(dirty) & 0xFFFFu;

    if (dmask) {
      // --- update dirty buckets + inline tie-aware scan over all 16
      float bv; int boi;
      if (dmask & 1u) dd[0] = fminf(dd[0], d2e(px[0], py[0], pz[0], qx, qy, qz));
      bv = dd[0]; boi = oi[0];
#pragma unroll
      for (int j = 1; j < 16; j++) {
        if (dmask & (1u << j))
          dd[j] = fminf(dd[j], d2e(px[j], py[j], pz[j], qx, qy, qz));
        bool better = (dd[j] > bv) || (dd[j] == bv && oi[j] < boi);
        bv = better ? dd[j] : bv; boi = better ? oi[j] : boi;
      }
      float vm = dpp_max_f32(bv);
      int ci = (bv == vm) ? boi : 0x7FFFFFFF;
      int widx = dpp_min_i32(ci);
      wkey = ((unsigned long long)(~__float_as_uint(vm)) << 32) | (unsigned)widx;
    }
    if (lane == 0) wred[t & 1][w] = wkey;
    __syncthreads();
  }

  // --- parallel writeback: inds + xyz from recorded winner indices
  for (int t = tid; t < NPOINT; t += 512) {
    int o = (int)sslot[t];
    float2 xy = sxy[o];
    out_inds[b * NPOINT + t] = (float)o;
    out_xyz[((size_t)b * NPOINT + t) * 3 + 0] = xy.x;
    out_xyz[((size_t)b * NPOINT + t) * 3 + 1] = xy.y;
    out_xyz[((size_t)b * NPOINT + t) * 3 + 2] = szl[o];
  }
}

// ---------------- prep: fold BN into per-channel consts ----------------------
// wsp floats: [0..255] A4[o]={sc0*W0x,sc0*W0y,sc0*W0z,sh0}; [256..319] sc1;
// [320..383] sh1; [384..511] sc2; [512..639] sh2; [640..703] sc0
__global__ __launch_bounds__(128) void prep_kernel(
    const float* __restrict__ W0, const float* __restrict__ g0,
    const float* __restrict__ b0, const float* __restrict__ m0,
    const float* __restrict__ v0, const float* __restrict__ g1,
    const float* __restrict__ b1, const float* __restrict__ m1,
    const float* __restrict__ v1, const float* __restrict__ g2,
    const float* __restrict__ b2, const float* __restrict__ m2,
    const float* __restrict__ v2, float* __restrict__ wsp) {
  const int tid = threadIdx.x;
  if (tid < 64) {
    float s0 = g0[tid] / sqrtf(v0[tid] + 1e-5f);
    wsp[4 * tid + 0] = s0 * W0[tid * K0 + 0];
    wsp[4 * tid + 1] = s0 * W0[tid * K0 + 1];
    wsp[4 * tid + 2] = s0 * W0[tid * K0 + 2];
    wsp[4 * tid + 3] = b0[tid] - m0[tid] * s0;
    wsp[640 + tid] = s0;
    float s1 = g1[tid] / sqrtf(v1[tid] + 1e-5f);
    wsp[256 + tid] = s1; wsp[320 + tid] = b1[tid] - m1[tid] * s1;
  }
  float s2 = g2[tid] / sqrtf(v2[tid] + 1e-5f);
  wsp[384 + tid] = s2; wsp[512 + tid] = b2[tid] - m2[tid] * s2;
}

// ---------------- zfeat: per-point L0 linear part ----------------------------
// szp[n][o] = sc0[o] * ( W0[o][0:3] . p_xyz + W0[o][3:67] . feat[:,n] )
__global__ __launch_bounds__(256) void zfeat_kernel(const float* __restrict__ xyz,
                                                    const float* __restrict__ feat,
                                                    const float* __restrict__ W0,
                                                    const float* __restrict__ wsp,
                                                    float* __restrict__ szp) {
  __shared__ float ftile[64][64];   // [c][u] - reads are wave-uniform
  __shared__ float sxyz[192];
  const int bt = blockIdx.x;        // b*128 + nt
  const int b = bt >> 7, nt = bt & 127;
  const int tid = threadIdx.x;
  const int lane = tid & 63, w = tid >> 6;

  const float* fb = feat + (size_t)b * 64 * NPTS + (size_t)nt * 64;
#pragma unroll
  for (int r = w; r < 64; r += 4)
    ftile[r][lane] = fb[(size_t)r * NPTS + lane];
  if (tid < 192)
    sxyz[tid] = xyz[((size_t)b * NPTS + (size_t)nt * 64) * 3 + tid];

  float w0x = W0[lane * K0 + 0], w0y = W0[lane * K0 + 1], w0z = W0[lane * K0 + 2];
  float wf[64];
#pragma unroll
  for (int i = 0; i < 64; i++) wf[i] = W0[lane * K0 + 3 + i];
  const float s0 = wsp[640 + lane];
  __syncthreads();

  float* ob = szp + ((size_t)b * NPTS + (size_t)nt * 64) * 64;
  for (int u = w; u < 64; u += 4) {
    float acc = w0x * sxyz[u * 3 + 0] + w0y * sxyz[u * 3 + 1] + w0z * sxyz[u * 3 + 2];
#pragma unroll
    for (int i = 0; i < 64; i++) acc = fmaf(wf[i], ftile[i][u], acc);
    ob[(size_t)u * 64 + lane] = acc * s0;
  }
}

// ---------------- ball query: one wave per query point -----------------------
__global__ __launch_bounds__(256) void ballq_kernel(const float* __restrict__ xyz,
                                                    const float* __restrict__ new_xyz,
                                                    int* __restrict__ ball) {
  const int lane = threadIdx.x & 63;
  const int q = blockIdx.x * 4 + (threadIdx.x >> 6);
  const int b = q >> 11;
  const float RR = (float)(0.4 * 0.4);
  const float cx = new_xyz[(size_t)q * 3 + 0];
  const float cy = new_xyz[(size_t)q * 3 + 1];
  const float cz = new_xyz[(size_t)q * 3 + 2];
  const float* xb = xyz + (size_t)b * NPTS * 3;
  int cnt = 0, firsti = -1;
  for (int base = 0; base < NPTS; base += 64) {
    int i = base + lane;
    float xx = xb[i * 3 + 0], yy = xb[i * 3 + 1], zz = xb[i * 3 + 2];
    float d2 = d2e(xx, yy, zz, cx, cy, cz);
    bool m = d2 < RR;
    unsigned long long mask = __ballot(m);
    if (mask) {
      if (firsti < 0) firsti = base + (__ffsll((unsigned long long)mask) - 1);
      int pos = cnt + (int)__popcll(mask & ((1ull << lane) - 1ull));
      if (m && pos < NSAMPLE) ball[(size_t)q * NSAMPLE + pos] = i;
      cnt += (int)__popcll(mask);
      if (cnt >= NSAMPLE) break;
    }
  }
  for (int s = cnt + lane; s < NSAMPLE; s += 64)
    ball[(size_t)q * NSAMPLE + s] = firsti;
}

// ---------------- MLP L1/L2 + max-pool: lane = channel, loop samples ---------
#define QPW 4
__global__ __launch_bounds__(256, 2) void mlp_kernel(
    const float* __restrict__ szp, const int* __restrict__ ball,
    const float* __restrict__ new_xyz, const float* __restrict__ W1,
    const float* __restrict__ W2, const float* __restrict__ wsp,
    float* __restrict__ out_feat) {
  __shared__ float ylds[4][64];
  __shared__ int   blds[4][64];
  const int tid = threadIdx.x;
  const int lane = tid & 63, wid = tid >> 6;

  float4 w1v[16], w2av[16], w2bv[16];
  const float4* W1r = (const float4*)(W1 + lane * 64);
  const float4* W2ar = (const float4*)(W2 + lane * 64);
  const float4* W2br = (const float4*)(W2 + (lane + 64) * 64);
#pragma unroll
  for (int i = 0; i < 16; i++) { w1v[i] = W1r[i]; w2av[i] = W2ar[i]; w2bv[i] = W2br[i]; }
  const float4 A = ((const float4*)wsp)[lane];
  const float sc1l = wsp[256 + lane], sh1l = wsp[320 + lane];
  const float sc2al = wsp[384 + lane], sh2al = wsp[512 + lane];
  const float sc2bl = wsp[448 + lane], sh2bl = wsp[576 + lane];

  for (int qi = 0; qi < QPW; qi++) {
    const int q = blockIdx.x * (4 * QPW) + qi * 4 + wid;
    const int b = q >> 11, p = q & 2047;

    const float cx = new_xyz[(size_t)q * 3 + 0];
    const float cy = new_xyz[(size_t)q * 3 + 1];
    const float cz = new_xyz[(size_t)q * 3 + 2];
    const float hc = A.w - (A.x * cx + A.y * cy + A.z * cz);

    blds[wid][lane] = ball[(size_t)q * NSAMPLE + lane];
    const float* szb = szp + (size_t)b * NPTS * 64;
    __builtin_amdgcn_s_waitcnt(0);   // vm+lgkm: blds visible to own wave

    float vA = 0.f, vB = 0.f;
    int idx0 = blds[wid][0];
    float fcur = szb[(size_t)idx0 * 64 + lane];
    const float4* yv = (const float4*)ylds[wid];

    for (int s = 0; s < NSAMPLE; s++) {
      int sn = (s < NSAMPLE - 1) ? s + 1 : s;
      int idxn = blds[wid][sn];
      float fnext = szb[(size_t)idxn * 64 + lane];

      float y0 = fmaxf(fcur + hc, 0.f);
      ylds[wid][lane] = y0;
      float a0 = 0.f, a1 = 0.f, a2 = 0.f, a3 = 0.f;
#pragma unroll
      for (int i = 0; i < 16; i++) {
        float4 y = yv[i];
        a0 = fmaf(w1v[i].x, y.x, a0);
        a1 = fmaf(w1v[i].y, y.y, a1);
        a2 = fmaf(w1v[i].z, y.z, a2);
        a3 = fmaf(w1v[i].w, y.w, a3);
      }
      float y1 = fmaxf(fmaf((a0 + a1) + (a2 + a3), sc1l, sh1l), 0.f);
      ylds[wid][lane] = y1;
      float c0 = 0.f, c1 = 0.f, c2 = 0.f, c3 = 0.f;
      float e0 = 0.f, e1 = 0.f, e2 = 0.f, e3 = 0.f;
#pragma unroll
      for (int i = 0; i < 16; i++) {
        float4 y = yv[i];
        c0 = fmaf(w2av[i].x, y.x, c0);
        c1 = fmaf(w2av[i].y, y.y, c1);
        c2 = fmaf(w2av[i].z, y.z, c2);
        c3 = fmaf(w2av[i].w, y.w, c3);
        e0 = fmaf(w2bv[i].x, y.x, e0);
        e1 = fmaf(w2bv[i].y, y.y, e1);
        e2 = fmaf(w2bv[i].z, y.z, e2);
        e3 = fmaf(w2bv[i].w, y.w, e3);
      }
      float y2a = fmaxf(fmaf((c0 + c1) + (c2 + c3), sc2al, sh2al), 0.f);
      float y2b = fmaxf(fmaf((e0 + e1) + (e2 + e3), sc2bl, sh2bl), 0.f);
      vA = fmaxf(vA, y2a);
      vB = fmaxf(vB, y2b);
      fcur = fnext;
    }
    out_feat[((size_t)b * C2 + lane) * NPOINT + p] = vA;
    out_feat[((size_t)b * C2 + lane + 64) * NPOINT + p] = vB;
  }
}

extern "C" void kernel_launch(void* const* d_in, const int* in_sizes, int n_in,
                              void* d_out, int out_size, void* d_ws, size_t ws_size,
                              hipStream_t stream) {
  const float* xyz  = (const float*)d_in[0];
  const float* feat = (const float*)d_in[1];
  const float* W0 = (const float*)d_in[2];
  const float* g0 = (const float*)d_in[3];
  const float* b0 = (const float*)d_in[4];
  const float* m0 = (const float*)d_in[5];
  const float* v0 = (const float*)d_in[6];
  const float* W1 = (const float*)d_in[7];
  const float* g1 = (const float*)d_in[8];
  const float* b1 = (const float*)d_in[9];
  const float* m1 = (const float*)d_in[10];
  const float* v1 = (const float*)d_in[11];
  const float* W2 = (const float*)d_in[12];
  const float* g2 = (const float*)d_in[13];
  const float* b2 = (const float*)d_in[14];
  const float* m2 = (const float*)d_in[15];
  const float* v2 = (const float*)d_in[16];

  float* out = (float*)d_out;
  float* out_xyz  = out;                         // (8,2048,3)   = 49152
  float* out_feat = out + 49152;                 // (8,128,2048) = 2097152
  float* out_inds = out + 49152 + 2097152;       // (8,2048)     = 16384

  int*   ball = (int*)d_ws;                                      // 4 MiB
  float* szp  = (float*)((char*)d_ws + 4194304);                 // 16.8 MiB
  float* wsp  = (float*)((char*)d_ws + 20971520);                // ~3 KiB

  hipLaunchKernelGGL(prep_kernel, dim3(1), dim3(128), 0, stream,
                     W0, g0, b0, m0, v0, g1, b1, m1, v1, g2, b2, m2, v2, wsp);
  hipLaunchKernelGGL(zfeat_kernel, dim3(BATCH * (NPTS / 64)), dim3(256), 0, stream,
                     xyz, feat, W0, wsp, szp);
  hipLaunchKernelGGL(fps_kernel, dim3(BATCH), dim3(512), 0, stream,
                     xyz, out_xyz, out_inds);
  hipLaunchKernelGGL(ballq_kernel, dim3((BATCH * NPOINT) / 4), dim3(256), 0, stream,
                     xyz, out_xyz, ball);
  hipLaunchKernelGGL(mlp_kernel, dim3((BATCH * NPOINT) / (4 * QPW)), dim3(256), 0, stream,
                     szp, ball, out_xyz, W1, W2, wsp, out_feat);
}

// Round 9
// 2686.276 us; speedup vs baseline: 7.6691x; 1.4703x over previous
//
#include <hip/hip_runtime.h>
#include <cstdint>
#include <cstddef>

#define BATCH   8
#define NPTS    8192
#define NPOINT  2048
#define NSAMPLE 64
#define K0      67      // 3 + 64 input channels
#define C2      128

// Exact-order squared distance, matching XLA/numpy: ((dx*dx + dy*dy) + dz*dz),
// separate mul/add (no FMA contraction), round-to-nearest f32.
__device__ __forceinline__ float d2e(float ax, float ay, float az,
                                     float bx, float by, float bz) {
#pragma clang fp contract(off)
  float dx = ax - bx;
  float dy = ay - by;
  float dz = az - bz;
  float t0 = dx * dx;
  float t1 = dy * dy;
  float t2 = dz * dz;
  return (t0 + t1) + t2;
}

// ---- wave64 reductions via DPP; result broadcast via readlane (uniform).
__device__ __forceinline__ float dpp_max_f32(float x) {
  int v;
  v = __builtin_amdgcn_update_dpp(__float_as_int(x), __float_as_int(x), 0xB1, 0xF, 0xF, false);
  x = fmaxf(x, __int_as_float(v));
  v = __builtin_amdgcn_update_dpp(__float_as_int(x), __float_as_int(x), 0x4E, 0xF, 0xF, false);
  x = fmaxf(x, __int_as_float(v));
  v = __builtin_amdgcn_update_dpp(__float_as_int(x), __float_as_int(x), 0x141, 0xF, 0xF, false);
  x = fmaxf(x, __int_as_float(v));
  v = __builtin_amdgcn_update_dpp(__float_as_int(x), __float_as_int(x), 0x140, 0xF, 0xF, false);
  x = fmaxf(x, __int_as_float(v));
  v = __builtin_amdgcn_update_dpp(__float_as_int(x), __float_as_int(x), 0x142, 0xA, 0xF, false);
  x = fmaxf(x, __int_as_float(v));
  v = __builtin_amdgcn_update_dpp(__float_as_int(x), __float_as_int(x), 0x143, 0xC, 0xF, false);
  x = fmaxf(x, __int_as_float(v));
  return __int_as_float(__builtin_amdgcn_readlane(__float_as_int(x), 63));
}

__device__ __forceinline__ int dpp_min_i32(int x) {
  int v;
  v = __builtin_amdgcn_update_dpp(x, x, 0xB1, 0xF, 0xF, false); x = min(x, v);
  v = __builtin_amdgcn_update_dpp(x, x, 0x4E, 0xF, 0xF, false); x = min(x, v);
  v = __builtin_amdgcn_update_dpp(x, x, 0x141, 0xF, 0xF, false); x = min(x, v);
  v = __builtin_amdgcn_update_dpp(x, x, 0x140, 0xF, 0xF, false); x = min(x, v);
  v = __builtin_amdgcn_update_dpp(x, x, 0x142, 0xA, 0xF, false); x = min(x, v);
  v = __builtin_amdgcn_update_dpp(x, x, 0x143, 0xC, 0xF, false); x = min(x, v);
  return __builtin_amdgcn_readlane(x, 63);
}

// ---------------- FPS: brute-force update, DPP reduce, 1 barrier/iter --------
// One block/batch, 8 waves, 512 threads. Thread tid owns contiguous points
// [tid*16, tid*16+16): global index = w*1024 + lane*16 + j is ascending in
// (wave, lane, j), so first-index argmax tie-break = strict-> per-thread scan,
// then min-index across lanes (DPP min), then min across waves (u64 key).
// Straight-line update (no prune, no branches): 16 d2e+fmin+scan per thread.
// Winner published as u64 key {~bits(val), idx} in LDS; winner index logged to
// u16 LDS buffer; single batched global writeback after the loop.
__global__ __launch_bounds__(512) void fps_kernel(const float* __restrict__ xyz,
                                                  float* __restrict__ out_xyz,
                                                  float* __restrict__ out_inds) {
  const int b = blockIdx.x;
  const int tid = threadIdx.x;
  const int lane = tid & 63, w = tid >> 6;

  __shared__ float2 sxy[NPTS];                  // original order
  __shared__ float  szl[NPTS];
  __shared__ unsigned short sslot[NPOINT];      // winner index per t
  __shared__ unsigned long long wred[2][8] __attribute__((aligned(16)));

  const float* xb = xyz + (size_t)b * NPTS * 3;

  // --- coalesced stage to LDS
  for (int k = 0; k < 16; k++) {
    int i = tid + k * 512;
    sxy[i] = make_float2(xb[i * 3 + 0], xb[i * 3 + 1]);
    szl[i] = xb[i * 3 + 2];
  }
  __syncthreads();

  const float2 q0xy = sxy[0];
  const float q0x = q0xy.x, q0y = q0xy.y, q0z = szl[0];

  // --- own 16 contiguous points in registers, init dd
  const int base = tid * 16;
  float px[16], py[16], pz[16], dd[16];
#pragma unroll
  for (int j = 0; j < 16; j++) {
    float2 xy = sxy[base + j];
    px[j] = xy.x; py[j] = xy.y; pz[j] = szl[base + j];
    dd[j] = d2e(px[j], py[j], pz[j], q0x, q0y, q0z);
  }
  if (tid == 0) sslot[0] = 0;

  // --- initial per-thread scan (strict >, ascending j = first index) + reduce
  {
    float bv = dd[0]; int bj = base;
#pragma unroll
    for (int j = 1; j < 16; j++) {
      bool better = dd[j] > bv;
      bv = better ? dd[j] : bv;
      bj = better ? base + j : bj;
    }
    float vm = dpp_max_f32(bv);
    int ci = (bv == vm) ? bj : 0x7FFFFFFF;
    int widx = dpp_min_i32(ci);
    if (lane == 0)
      wred[0][w] = ((unsigned long long)(~__float_as_uint(vm)) << 32) | (unsigned)widx;
  }
  __syncthreads();

  for (int t = 1; t < NPOINT; ++t) {
    // --- global winner = min of 8 wave keys (vectorized broadcast reads)
    const ulonglong2* wv = (const ulonglong2*)wred[(t - 1) & 1];
    ulonglong2 p0 = wv[0], p1 = wv[1], p2 = wv[2], p3 = wv[3];
    unsigned long long g0 = (p0.y < p0.x) ? p0.y : p0.x;
    unsigned long long g1 = (p1.y < p1.x) ? p1.y : p1.x;
    unsigned long long g2 = (p2.y < p2.x) ? p2.y : p2.x;
    unsigned long long g3 = (p3.y < p3.x) ? p3.y : p3.x;
    g0 = (g1 < g0) ? g1 : g0; g2 = (g3 < g2) ? g3 : g2;
    g0 = (g2 < g0) ? g2 : g0;
    const int nxt = (int)(g0 & 0xFFFFFFFFu);
    const float2 qxy = sxy[nxt];
    const float qx = qxy.x, qy = qxy.y, qz = szl[nxt];
    if (tid == 0) sslot[t] = (unsigned short)nxt;

    // --- straight-line update + tie-aware scan (no branches)
    float d0 = d2e(px[0], py[0], pz[0], qx, qy, qz);
    dd[0] = fminf(dd[0], d0);
    float bv = dd[0]; int bj = base;
#pragma unroll
    for (int j = 1; j < 16; j++) {
      float d = d2e(px[j], py[j], pz[j], qx, qy, qz);
      dd[j] = fminf(dd[j], d);
      bool better = dd[j] > bv;
      bv = better ? dd[j] : bv;
      bj = better ? base + j : bj;
    }
    float vm = dpp_max_f32(bv);
    int ci = (bv == vm) ? bj : 0x7FFFFFFF;
    int widx = dpp_min_i32(ci);
    if (lane == 0)
      wred[t & 1][w] = ((unsigned long long)(~__float_as_uint(vm)) << 32) | (unsigned)widx;
    __syncthreads();
  }

  // --- parallel writeback: inds + xyz from recorded winner indices
  for (int t = tid; t < NPOINT; t += 512) {
    int o = (int)sslot[t];
    float2 xy = sxy[o];
    out_inds[b * NPOINT + t] = (float)o;
    out_xyz[((size_t)b * NPOINT + t) * 3 + 0] = xy.x;
    out_xyz[((size_t)b * NPOINT + t) * 3 + 1] = xy.y;
    out_xyz[((size_t)b * NPOINT + t) * 3 + 2] = szl[o];
  }
}

// ---------------- prep: fold BN into per-channel consts ----------------------
// wsp floats: [0..255] A4[o]={sc0*W0x,sc0*W0y,sc0*W0z,sh0}; [256..319] sc1;
// [320..383] sh1; [384..511] sc2; [512..639] sh2; [640..703] sc0
__global__ __launch_bounds__(128) void prep_kernel(
    const float* __restrict__ W0, const float* __restrict__ g0,
    const float* __restrict__ b0, const float* __restrict__ m0,
    const float* __restrict__ v0, const float* __restrict__ g1,
    const float* __restrict__ b1, const float* __restrict__ m1,
    const float* __restrict__ v1, const float* __restrict__ g2,
    const float* __restrict__ b2, const float* __restrict__ m2,
    const float* __restrict__ v2, float* __restrict__ wsp) {
  const int tid = threadIdx.x;
  if (tid < 64) {
    float s0 = g0[tid] / sqrtf(v0[tid] + 1e-5f);
    wsp[4 * tid + 0] = s0 * W0[tid * K0 + 0];
    wsp[4 * tid + 1] = s0 * W0[tid * K0 + 1];
    wsp[4 * tid + 2] = s0 * W0[tid * K0 + 2];
    wsp[4 * tid + 3] = b0[tid] - m0[tid] * s0;
    wsp[640 + tid] = s0;
    float s1 = g1[tid] / sqrtf(v1[tid] + 1e-5f);
    wsp[256 + tid] = s1; wsp[320 + tid] = b1[tid] - m1[tid] * s1;
  }
  float s2 = g2[tid] / sqrtf(v2[tid] + 1e-5f);
  wsp[384 + tid] = s2; wsp[512 + tid] = b2[tid] - m2[tid] * s2;
}

// ---------------- zfeat: per-point L0 linear part ----------------------------
// szp[n][o] = sc0[o] * ( W0[o][0:3] . p_xyz + W0[o][3:67] . feat[:,n] )
__global__ __launch_bounds__(256) void zfeat_kernel(const float* __restrict__ xyz,
                                                    const float* __restrict__ feat,
                                                    const float* __restrict__ W0,
                                                    const float* __restrict__ wsp,
                                                    float* __restrict__ szp) {
  __shared__ float ftile[64][64];   // [c][u] - reads are wave-uniform
  __shared__ float sxyz[192];
  const int bt = blockIdx.x;        // b*128 + nt
  const int b = bt >> 7, nt = bt & 127;
  const int tid = threadIdx.x;
  const int lane = tid & 63, w = tid >> 6;

  const float* fb = feat + (size_t)b * 64 * NPTS + (size_t)nt * 64;
#pragma unroll
  for (int r = w; r < 64; r += 4)
    ftile[r][lane] = fb[(size_t)r * NPTS + lane];
  if (tid < 192)
    sxyz[tid] = xyz[((size_t)b * NPTS + (size_t)nt * 64) * 3 + tid];

  float w0x = W0[lane * K0 + 0], w0y = W0[lane * K0 + 1], w0z = W0[lane * K0 + 2];
  float wf[64];
#pragma unroll
  for (int i = 0; i < 64; i++) wf[i] = W0[lane * K0 + 3 + i];
  const float s0 = wsp[640 + lane];
  __syncthreads();

  float* ob = szp + ((size_t)b * NPTS + (size_t)nt * 64) * 64;
  for (int u = w; u < 64; u += 4) {
    float acc = w0x * sxyz[u * 3 + 0] + w0y * sxyz[u * 3 + 1] + w0z * sxyz[u * 3 + 2];
#pragma unroll
    for (int i = 0; i < 64; i++) acc = fmaf(wf[i], ftile[i][u], acc);
    ob[(size_t)u * 64 + lane] = acc * s0;
  }
}

// ---------------- ball query: one wave per query point -----------------------
__global__ __launch_bounds__(256) void ballq_kernel(const float* __restrict__ xyz,
                                                    const float* __restrict__ new_xyz,
                                                    int* __restrict__ ball) {
  const int lane = threadIdx.x & 63;
  const int q = blockIdx.x * 4 + (threadIdx.x >> 6);
  const int b = q >> 11;
  const float RR = (float)(0.4 * 0.4);
  const float cx = new_xyz[(size_t)q * 3 + 0];
  const float cy = new_xyz[(size_t)q * 3 + 1];
  const float cz = new_xyz[(size_t)q * 3 + 2];
  const float* xb = xyz + (size_t)b * NPTS * 3;
  int cnt = 0, firsti = -1;
  for (int base = 0; base < NPTS; base += 64) {
    int i = base + lane;
    float xx = xb[i * 3 + 0], yy = xb[i * 3 + 1], zz = xb[i * 3 + 2];
    float d2 = d2e(xx, yy, zz, cx, cy, cz);
    bool m = d2 < RR;
    unsigned long long mask = __ballot(m);
    if (mask) {
      if (firsti < 0) firsti = base + (__ffsll((unsigned long long)mask) - 1);
      int pos = cnt + (int)__popcll(mask & ((1ull << lane) - 1ull));
      if (m && pos < NSAMPLE) ball[(size_t)q * NSAMPLE + pos] = i;
      cnt += (int)__popcll(mask);
      if (cnt >= NSAMPLE) break;
    }
  }
  for (int s = cnt + lane; s < NSAMPLE; s += 64)
    ball[(size_t)q * NSAMPLE + s] = firsti;
}

// ---------------- MLP L1/L2 + max-pool: lane = channel, loop samples ---------
#define QPW 4
__global__ __launch_bounds__(256, 2) void mlp_kernel(
    const float* __restrict__ szp, const int* __restrict__ ball,
    const float* __restrict__ new_xyz, const float* __restrict__ W1,
    const float* __restrict__ W2, const float* __restrict__ wsp,
    float* __restrict__ out_feat) {
  __shared__ float ylds[4][64];
  __shared__ int   blds[4][64];
  const int tid = threadIdx.x;
  const int lane = tid & 63, wid = tid >> 6;

  float4 w1v[16], w2av[16], w2bv[16];
  const float4* W1r = (const float4*)(W1 + lane * 64);
  const float4* W2ar = (const float4*)(W2 + lane * 64);
  const float4* W2br = (const float4*)(W2 + (lane + 64) * 64);
#pragma unroll
  for (int i = 0; i < 16; i++) { w1v[i] = W1r[i]; w2av[i] = W2ar[i]; w2bv[i] = W2br[i]; }
  const float4 A = ((const float4*)wsp)[lane];
  const float sc1l = wsp[256 + lane], sh1l = wsp[320 + lane];
  const float sc2al = wsp[384 + lane], sh2al = wsp[512 + lane];
  const float sc2bl = wsp[448 + lane], sh2bl = wsp[576 + lane];

  for (int qi = 0; qi < QPW; qi++) {
    const int q = blockIdx.x * (4 * QPW) + qi * 4 + wid;
    const int b = q >> 11, p = q & 2047;

    const float cx = new_xyz[(size_t)q * 3 + 0];
    const float cy = new_xyz[(size_t)q * 3 + 1];
    const float cz = new_xyz[(size_t)q * 3 + 2];
    const float hc = A.w - (A.x * cx + A.y * cy + A.z * cz);

    blds[wid][lane] = ball[(size_t)q * NSAMPLE + lane];
    const float* szb = szp + (size_t)b * NPTS * 64;
    __builtin_amdgcn_s_waitcnt(0);   // vm+lgkm: blds visible to own wave

    float vA = 0.f, vB = 0.f;
    int idx0 = blds[wid][0];
    float fcur = szb[(size_t)idx0 * 64 + lane];
    const float4* yv = (const float4*)ylds[wid];

    for (int s = 0; s < NSAMPLE; s++) {
      int sn = (s < NSAMPLE - 1) ? s + 1 : s;
      int idxn = blds[wid][sn];
      float fnext = szb[(size_t)idxn * 64 + lane];

      float y0 = fmaxf(fcur + hc, 0.f);
      ylds[wid][lane] = y0;
      float a0 = 0.f, a1 = 0.f, a2 = 0.f, a3 = 0.f;
#pragma unroll
      for (int i = 0; i < 16; i++) {
        float4 y = yv[i];
        a0 = fmaf(w1v[i].x, y.x, a0);
        a1 = fmaf(w1v[i].y, y.y, a1);
        a2 = fmaf(w1v[i].z, y.z, a2);
        a3 = fmaf(w1v[i].w, y.w, a3);
      }
      float y1 = fmaxf(fmaf((a0 + a1) + (a2 + a3), sc1l, sh1l), 0.f);
      ylds[wid][lane] = y1;
      float c0 = 0.f, c1 = 0.f, c2 = 0.f, c3 = 0.f;
      float e0 = 0.f, e1 = 0.f, e2 = 0.f, e3 = 0.f;
#pragma unroll
      for (int i = 0; i < 16; i++) {
        float4 y = yv[i];
        c0 = fmaf(w2av[i].x, y.x, c0);
        c1 = fmaf(w2av[i].y, y.y, c1);
        c2 = fmaf(w2av[i].z, y.z, c2);
        c3 = fmaf(w2av[i].w, y.w, c3);
        e0 = fmaf(w2bv[i].x, y.x, e0);
        e1 = fmaf(w2bv[i].y, y.y, e1);
        e2 = fmaf(w2bv[i].z, y.z, e2);
        e3 = fmaf(w2bv[i].w, y.w, e3);
      }
      float y2a = fmaxf(fmaf((c0 + c1) + (c2 + c3), sc2al, sh2al), 0.f);
      float y2b = fmaxf(fmaf((e0 + e1) + (e2 + e3), sc2bl, sh2bl), 0.f);
      vA = fmaxf(vA, y2a);
      vB = fmaxf(vB, y2b);
      fcur = fnext;
    }
    out_feat[((size_t)b * C2 + lane) * NPOINT + p] = vA;
    out_feat[((size_t)b * C2 + lane + 64) * NPOINT + p] = vB;
  }
}

extern "C" void kernel_launch(void* const* d_in, const int* in_sizes, int n_in,
                              void* d_out, int out_size, void* d_ws, size_t ws_size,
                              hipStream_t stream) {
  const float* xyz  = (const float*)d_in[0];
  const float* feat = (const float*)d_in[1];
  const float* W0 = (const float*)d_in[2];
  const float* g0 = (const float*)d_in[3];
  const float* b0 = (const float*)d_in[4];
  const float* m0 = (const float*)d_in[5];
  const float* v0 = (const float*)d_in[6];
  const float* W1 = (const float*)d_in[7];
  const float* g1 = (const float*)d_in[8];
  const float* b1 = (const float*)d_in[9];
  const float* m1 = (const float*)d_in[10];
  const float* v1 = (const float*)d_in[11];
  const float* W2 = (const float*)d_in[12];
  const float* g2 = (const float*)d_in[13];
  const float* b2 = (const float*)d_in[14];
  const float* m2 = (const float*)d_in[15];
  const float* v2 = (const float*)d_in[16];

  float* out = (float*)d_out;
  float* out_xyz  = out;                         // (8,2048,3)   = 49152
  float* out_feat = out + 49152;                 // (8,128,2048) = 2097152
  float* out_inds = out + 49152 + 2097152;       // (8,2048)     = 16384

  int*   ball = (int*)d_ws;                                      // 4 MiB
  float* szp  = (float*)((char*)d_ws + 4194304);                 // 16.8 MiB
  float* wsp  = (float*)((char*)d_ws + 20971520);                // ~3 KiB

  hipLaunchKernelGGL(prep_kernel, dim3(1), dim3(128), 0, stream,
                     W0, g0, b0, m0, v0, g1, b1, m1, v1, g2, b2, m2, v2, wsp);
  hipLaunchKernelGGL(zfeat_kernel, dim3(BATCH * (NPTS / 64)), dim3(256), 0, stream,
                     xyz, feat, W0, wsp, szp);
  hipLaunchKernelGGL(fps_kernel, dim3(BATCH), dim3(512), 0, stream,
                     xyz, out_xyz, out_inds);
  hipLaunchKernelGGL(ballq_kernel, dim3((BATCH * NPOINT) / 4), dim3(256), 0, stream,
                     xyz, out_xyz, ball);
  hipLaunchKernelGGL(mlp_kernel, dim3((BATCH * NPOINT) / (4 * QPW)), dim3(256), 0, stream,
                     szp, ball, out_xyz, W1, W2, wsp, out_feat);
}